// Round 19
// baseline (297.631 us; speedup 1.0000x reference)
//
#include <hip/hip_runtime.h>

// SpikingNetwork: B=128 T=128 I=1024 H1=2048 H2=2048 O=512
// R19 = R18 with GEMM1 ported to the VERIFIED i8-GEMM2 counted-vmcnt
//   schedule: BK=32, 3x32KB LDS slots, stage t+2, VMC(4) once/tile (never
//   drains in main loop — T4), 2 phases/tile (MH0/MH1), 2 bars/tile,
//   64B-row swizzle chunk^((row>>1)&3). Ledger byte-identical to R18's
//   GEMM2-i8 (verified); only MFMA intrinsic, NKT=96, and the 3-term
//   aoff/boff mapping differ. Accumulation order identical -> absmax
//   bit-identical (0.03515625 expected).
// GEMM2-i8, quant, splits, GEMM3 unchanged from R18.

typedef unsigned long long u64;
typedef __attribute__((ext_vector_type(4))) float f32x4;
typedef __attribute__((ext_vector_type(8))) short bf16x8;
typedef __attribute__((ext_vector_type(4))) int i32x4;

__device__ __forceinline__ unsigned short f2bf(float f) {
  unsigned u = __float_as_uint(f);
  u += 0x7fff + ((u >> 16) & 1);   // RNE
  return (unsigned short)(u >> 16);
}
__device__ __forceinline__ float bf2f(unsigned short h) {
  return __uint_as_float(((unsigned)h) << 16);
}
__device__ __forceinline__ void gld_lds16(const void* g, void* l) {
  __builtin_amdgcn_global_load_lds((const __attribute__((address_space(1))) void*)g,
                                   (__attribute__((address_space(3))) void*)l, 16, 0, 0);
}

// src: R x K f32 (K = 1<<lgK) -> dst: R x 2K bf16 rows [hi | lo], 4 elem/thread
__global__ void k_split4(const float4* __restrict__ src, unsigned short* __restrict__ dst,
                         int lgK, size_t total4) {
  size_t i = (size_t)blockIdx.x * 256 + threadIdx.x;
  if (i >= total4) return;
  const int K = 1 << lgK;
  size_t e = i << 2;
  size_t r = e >> lgK;
  int k = (int)(e & (size_t)(K - 1));
  float4 f = src[i];
  unsigned short h0 = f2bf(f.x), h1 = f2bf(f.y), h2 = f2bf(f.z), h3 = f2bf(f.w);
  unsigned short l0 = f2bf(f.x - bf2f(h0)), l1 = f2bf(f.y - bf2f(h1));
  unsigned short l2 = f2bf(f.z - bf2f(h2)), l3 = f2bf(f.w - bf2f(h3));
  size_t o = (r << (lgK + 1)) + (size_t)k;
  *(u64*)(dst + o)     = (u64)h0 | ((u64)h1 << 16) | ((u64)h2 << 32) | ((u64)h3 << 48);
  *(u64*)(dst + o + K) = (u64)l0 | ((u64)l1 << 16) | ((u64)l2 << 32) | ((u64)l3 << 48);
}

// per-row int8 quantization of W2 (2048 x 2048): one block per row
__global__ void k_quant_w2(const float* __restrict__ W2, signed char* __restrict__ W2q,
                           float* __restrict__ scl) {
  __shared__ float red[4];
  const int r = blockIdx.x;
  const int tid = threadIdx.x;
  const float* row = W2 + (size_t)r * 2048;
  float vbuf[8];
  float mx = 0.f;
#pragma unroll
  for (int k = 0; k < 8; ++k) {
    vbuf[k] = row[tid + k * 256];
    mx = fmaxf(mx, fabsf(vbuf[k]));
  }
#pragma unroll
  for (int o = 32; o; o >>= 1) mx = fmaxf(mx, __shfl_xor(mx, o));
  if ((tid & 63) == 0) red[tid >> 6] = mx;
  __syncthreads();
  mx = fmaxf(fmaxf(red[0], red[1]), fmaxf(red[2], red[3]));
  mx = fmaxf(mx, 1e-20f);
  const float inv = 127.f / mx;
  if (tid == 0) scl[r] = mx * (1.f / 127.f);
#pragma unroll
  for (int k = 0; k < 8; ++k)
    W2q[(size_t)r * 2048 + tid + k * 256] = (signed char)__float2int_rn(vbuf[k] * inv);
}

// 4x ds_read_b128, stride 1024 B (16-row frag groups on 64B rows)
#define DSR4_64(D, BASE)                                                       \
  do {                                                                         \
    asm volatile("ds_read_b128 %0, %1" : "=v"(D[0]) : "v"(BASE));              \
    asm volatile("ds_read_b128 %0, %1 offset:1024" : "=v"(D[1]) : "v"(BASE));  \
    asm volatile("ds_read_b128 %0, %1 offset:2048" : "=v"(D[2]) : "v"(BASE));  \
    asm volatile("ds_read_b128 %0, %1 offset:3072" : "=v"(D[3]) : "v"(BASE));  \
  } while (0)
#define WAITL(N)                                                               \
  do {                                                                         \
    asm volatile("s_waitcnt lgkmcnt(" #N ")" ::: "memory");                    \
    __builtin_amdgcn_sched_barrier(0);                                         \
  } while (0)
#define VMC(N)                                                                 \
  do {                                                                         \
    asm volatile("s_waitcnt vmcnt(" #N ")" ::: "memory");                      \
    __builtin_amdgcn_sched_barrier(0);                                         \
  } while (0)
#define BAR() __builtin_amdgcn_s_barrier()
#define SP1() __builtin_amdgcn_s_setprio(1)
#define SP0() __builtin_amdgcn_s_setprio(0)
#define MFMA16(MH, AF, BG)                                                     \
  _Pragma("unroll")                                                            \
  for (int m = 0; m < 4; ++m)                                                  \
    _Pragma("unroll")                                                          \
    for (int n = 0; n < 4; ++n)                                                \
      acc[(MH)*4 + m][n] = __builtin_amdgcn_mfma_f32_16x16x32_bf16(            \
          AF[m], BG[n], acc[(MH)*4 + m][n], 0, 0, 0);
#define MFMA16_I8(MH, AF, BG)                                                  \
  _Pragma("unroll")                                                            \
  for (int m = 0; m < 4; ++m)                                                  \
    _Pragma("unroll")                                                          \
    for (int n = 0; n < 4; ++n)                                                \
      acc[(MH)*4 + m][n] = __builtin_amdgcn_mfma_i32_16x16x64_i8(              \
          AF[m], BG[n], acc[(MH)*4 + m][n], 0, 0, 0);

// ---- GEMM1 + LIF1: 3-term split-bf16, K'=3072, BK=32, counted vmcnt ----
// out: S1 as u8 (0/1), [rows][2048] bytes.
__global__ __launch_bounds__(512, 2)
void k_gemm1_lif(const unsigned short* __restrict__ A,
                 const unsigned short* __restrict__ Bw,
                 const float* __restrict__ bias,
                 unsigned char* __restrict__ out) {
  __shared__ __align__(128) char lds[132096];  // 3x32KB slots; epi 128x258 f32
  const int NKT = 96;                          // K' = 3072, BK = 32
  const int tid  = threadIdx.x;
  const int lane = tid & 63;
  const int w    = tid >> 6;
  const int wm = w >> 2, wn = w & 3;
  const int wr = wm * 128, wc = wn * 64;
  const int lrow = lane & 15, t4 = lane >> 4;
  const int brow = blockIdx.x * 256, bcol = blockIdx.y * 256;

  f32x4 acc[8][4];
#pragma unroll
  for (int m = 0; m < 8; ++m)
#pragma unroll
    for (int n = 0; n < 4; ++n) acc[m][n] = (f32x4){0.f, 0.f, 0.f, 0.f};

  // staging: A 256x32 bf16 (16KB, 1024 chunks) + B same; 2+2 per thread.
  // 64B rows -> swizzle chunk ^ ((row>>1)&3). Source col pre-swizzled.
  int voffA[2], voffB[2];
  unsigned dstA[2], dstB[2];
#pragma unroll
  for (int j = 0; j < 2; ++j) {
    const int c = tid + j * 512;             // 0..1023
    const int r = c >> 2;                    // 4 chunks per 64B row
    const int sc = ((c & 3) ^ ((r >> 1) & 3)) * 8;   // elements (16B=8 bf16)
    voffA[j] = (brow + r) * 2048 + sc;
    voffB[j] = (bcol + r) * 2048 + sc;
    dstA[j] = (unsigned)c * 16;
    dstB[j] = 16384u + (unsigned)c * 16;
  }
  auto stage_tile = [&](int tt) {
    if (tt >= NKT) return;
    const int kb = tt * 32;
    const int aoff = (kb < 1024) ? kb : kb - 1024;    // [Xhi,Xhi,Xlo]
    const int boff = (kb < 2048) ? kb : kb - 2048;    // [W1hi,W1lo,W1hi]
    const unsigned short* Ap = A + aoff;
    const unsigned short* Bp = Bw + boff;
    char* slot = lds + (tt % 3) * 32768;
#pragma unroll
    for (int j = 0; j < 2; ++j)
      gld_lds16(Ap + voffA[j], slot + dstA[j]);
#pragma unroll
    for (int j = 0; j < 2; ++j)
      gld_lds16(Bp + voffB[j], slot + dstB[j]);
  };

  const unsigned ldsb = (unsigned)(size_t)(__attribute__((address_space(3))) char*)lds;
  const unsigned cA  = (unsigned)((wr + lrow) * 64);
  const unsigned cB  = 16384u + (unsigned)((wc + lrow) * 64);
  const unsigned chi = (unsigned)((t4 ^ ((lrow >> 1) & 3)) * 16);

  bf16x8 afA[4], afB[4], bgA[4], bgB[4];

  // prologue: tiles 0,1 staged; tile 0 landed (tile 1 in flight); p0 reads
  stage_tile(0); stage_tile(1);
  VMC(4);
  BAR();
  DSR4_64(afA, ldsb + cA + chi);
  DSR4_64(bgA, ldsb + cB + chi);

  // per tile (verified i8 ledger): p0 {stage(t+2); VMC(4); BAR; read afB;
  // WAITL(4); MFMA(0)}  p1 {read afA,BGN of t+1; WAITL(8); MFMA(1); BAR}
#define TILE_B32(T, BGC, BGN)                                                  \
  {                                                                            \
    const int tt = (T);                                                        \
    const unsigned s  = ldsb + (unsigned)((tt % 3) * 32768);                   \
    const unsigned sn = ldsb + (unsigned)(((tt + 1) % 3) * 32768);             \
    stage_tile(tt + 2);                                                        \
    if (tt + 2 < NKT) { VMC(4); } else { VMC(0); }  /* tile tt+1 landed */     \
    BAR();                                                                     \
    DSR4_64(afB, s + cA + 4096 + chi);                                         \
    WAITL(4);                                                                  \
    SP1(); MFMA16(0, afA, BGC); SP0();                                         \
    if (tt + 1 < NKT) {                                                        \
      DSR4_64(afA, sn + cA + chi);                                             \
      DSR4_64(BGN, sn + cB + chi);                                             \
      WAITL(8);                                                                \
    } else {                                                                   \
      WAITL(0);                                                                \
    }                                                                          \
    SP1(); MFMA16(1, afB, BGC); SP0();                                         \
    BAR();                                                                     \
  }

#pragma unroll 1
  for (int t = 0; t < NKT; t += 2) {
    TILE_B32(t, bgA, bgB);
    TILE_B32(t + 1, bgB, bgA);
  }
#undef TILE_B32

  // fused LIF1 epilogue: spikes as u8
  float* Ct = (float*)lds;
  const int colT  = tid & 255;
  const int batch = tid >> 8;
  const float bs = bias[bcol + colT];
  float v = 0.f;
  unsigned char* sp = out + (size_t)(brow + batch * 128) * 2048 + bcol + colT;
#pragma unroll
  for (int h = 0; h < 2; ++h) {
    __syncthreads();
#pragma unroll
    for (int mm = 0; mm < 4; ++mm) {
      const int m = h * 4 + mm;
#pragma unroll
      for (int n = 0; n < 4; ++n) {
        const int lr  = wm * 64 + mm * 16 + t4 * 4;
        const int col = wc + n * 16 + lrow;
#pragma unroll
        for (int r = 0; r < 4; ++r) Ct[(lr + r) * 258 + col] = acc[m][n][r];
      }
    }
    __syncthreads();
#pragma unroll 4
    for (int tl = 0; tl < 64; ++tl) {
      const float xx = Ct[(batch * 64 + tl) * 258 + colT] + bs;
      v = 0.9f * xx + v - ((xx > 1.0f) ? 1.0f : 0.0f);
      sp[(size_t)(h * 64 + tl) * 2048] = (v > 1.0f) ? 1 : 0;
    }
  }
}

// ---- GEMM2 + LIF2, int8 (unchanged from R18) ----
__global__ __launch_bounds__(512, 2)
void k_gemm2_lif_i8(const signed char* __restrict__ A,
                    const signed char* __restrict__ Bq,
                    const float* __restrict__ scl,
                    const float* __restrict__ bias,
                    unsigned short* __restrict__ out, int b0) {
  __shared__ __align__(128) char lds[132096];  // 3x32KB slots; epi 128x258
  const int NKT = 32;
  const int tid  = threadIdx.x;
  const int lane = tid & 63;
  const int w    = tid >> 6;
  const int wm = w >> 2, wn = w & 3;
  const int wr = wm * 128, wc = wn * 64;
  const int lrow = lane & 15, t4 = lane >> 4;
  const int brow = blockIdx.x * 256, bcol = blockIdx.y * 256;

  i32x4 acc[8][4];
#pragma unroll
  for (int m = 0; m < 8; ++m)
#pragma unroll
    for (int n = 0; n < 4; ++n) acc[m][n] = (i32x4){0, 0, 0, 0};

  int voffA[2], voffB[2];
  unsigned dstA[2], dstB[2];
#pragma unroll
  for (int j = 0; j < 2; ++j) {
    const int c = tid + j * 512;             // 0..1023
    const int r = c >> 2;
    const int sc = ((c & 3) ^ ((r >> 1) & 3)) * 16;
    voffA[j] = (brow + r) * 2048 + sc;
    voffB[j] = (bcol + r) * 2048 + sc;
    dstA[j] = (unsigned)c * 16;
    dstB[j] = 16384u + (unsigned)c * 16;
  }
  auto stage_tile = [&](int tt) {
    if (tt >= NKT) return;
    const int kb = tt * 64;
    char* slot = lds + (tt % 3) * 32768;
#pragma unroll
    for (int j = 0; j < 2; ++j)
      gld_lds16(A + kb + voffA[j], slot + dstA[j]);
#pragma unroll
    for (int j = 0; j < 2; ++j)
      gld_lds16(Bq + kb + voffB[j], slot + dstB[j]);
  };

  const unsigned ldsb = (unsigned)(size_t)(__attribute__((address_space(3))) char*)lds;
  const unsigned cA  = (unsigned)((wr + lrow) * 64);
  const unsigned cB  = 16384u + (unsigned)((wc + lrow) * 64);
  const unsigned chi = (unsigned)((t4 ^ ((lrow >> 1) & 3)) * 16);

  i32x4 afA[4], afB[4], bgA[4], bgB[4];

  stage_tile(0); stage_tile(1);
  VMC(4);
  BAR();
  DSR4_64(afA, ldsb + cA + chi);
  DSR4_64(bgA, ldsb + cB + chi);

#define TILE_I8(T, BGC, BGN)                                                   \
  {                                                                            \
    const int tt = (T);                                                        \
    const unsigned s  = ldsb + (unsigned)((tt % 3) * 32768);                   \
    const unsigned sn = ldsb + (unsigned)(((tt + 1) % 3) * 32768);             \
    stage_tile(tt + 2);                                                        \
    if (tt + 2 < NKT) { VMC(4); } else { VMC(0); }                             \
    BAR();                                                                     \
    DSR4_64(afB, s + cA + 4096 + chi);                                         \
    WAITL(4);                                                                  \
    SP1(); MFMA16_I8(0, afA, BGC); SP0();                                      \
    if (tt + 1 < NKT) {                                                        \
      DSR4_64(afA, sn + cA + chi);                                             \
      DSR4_64(BGN, sn + cB + chi);                                             \
      WAITL(8);                                                                \
    } else {                                                                   \
      WAITL(0);                                                                \
    }                                                                          \
    SP1(); MFMA16_I8(1, afB, BGC); SP0();                                      \
    BAR();                                                                     \
  }

#pragma unroll 1
  for (int t = 0; t < NKT; t += 2) {
    TILE_I8(t, bgA, bgB);
    TILE_I8(t + 1, bgB, bgA);
  }
#undef TILE_I8

  // fused LIF2 epilogue
  int* Cti = (int*)lds;
  const int colT  = tid & 255;
  const int batch = tid >> 8;
  const float bs = bias[bcol + colT];
  const float sc = scl[bcol + colT];
  float v = 0.f;
  int cnt = 0;
#pragma unroll
  for (int h = 0; h < 2; ++h) {
    __syncthreads();
#pragma unroll
    for (int mm = 0; mm < 4; ++mm) {
      const int m = h * 4 + mm;
#pragma unroll
      for (int n = 0; n < 4; ++n) {
        const int lr  = wm * 64 + mm * 16 + t4 * 4;
        const int col = wc + n * 16 + lrow;
#pragma unroll
        for (int r = 0; r < 4; ++r) Cti[(lr + r) * 258 + col] = acc[m][n][r];
      }
    }
    __syncthreads();
#pragma unroll 4
    for (int tl = 0; tl < 64; ++tl) {
      const float xx = (float)Cti[(batch * 64 + tl) * 258 + colT] * sc + bs;
      v = 0.9f * xx + v - ((xx > 1.0f) ? 1.0f : 0.0f);
      cnt += (v > 1.0f);
    }
  }
  out[(size_t)(b0 + 2 * blockIdx.x + batch) * 2048 + bcol + colT] =
      f2bf((float)cnt * 0.0078125f);
}

// out(128x512) += ACC(128x2048 bf16) @ Wocat^T over K-slice z*256..+256, atomic
__global__ void k_gemm3(const unsigned short* __restrict__ A,
                        const unsigned short* __restrict__ B,
                        float* __restrict__ C) {
  __shared__ __align__(16) unsigned short Asm[128 * 64];
  __shared__ __align__(16) unsigned short Bsm[128 * 64];
  const int tid  = threadIdx.x;
  const int bcol = blockIdx.y * 128;
  const int k0   = blockIdx.z * 256;
  const int lane = tid & 63;
  const int w    = tid >> 6;
  const int wr = (w >> 1) * 64, wc = (w & 1) * 64;
  const int lrow = lane & 15, lk = (lane >> 4) * 8;

  f32x4 acc[4][4];
#pragma unroll
  for (int m = 0; m < 4; ++m)
#pragma unroll
    for (int n = 0; n < 4; ++n) acc[m][n] = (f32x4){0.f, 0.f, 0.f, 0.f};

  for (int kt = 0; kt < 4; ++kt) {
    const int kb = k0 + kt * 64;
#pragma unroll
    for (int i = 0; i < 4; ++i) {
      int c = tid + i * 256;
      int row = c >> 3, kc = (c & 7) * 8;
      gld_lds16(A + (size_t)row * 2048 + (kb & 2047) + kc, &Asm[c * 8]);
      gld_lds16(B + (size_t)(bcol + row) * 4096 + kb + kc, &Bsm[c * 8]);
    }
    __syncthreads();
#pragma unroll
    for (int ks = 0; ks < 2; ++ks) {
      bf16x8 af[4], bg[4];
#pragma unroll
      for (int m = 0; m < 4; ++m)
        af[m] = *(const bf16x8*)&Asm[(wr + m * 16 + lrow) * 64 + ks * 32 + lk];
#pragma unroll
      for (int n = 0; n < 4; ++n)
        bg[n] = *(const bf16x8*)&Bsm[(wc + n * 16 + lrow) * 64 + ks * 32 + lk];
#pragma unroll
      for (int m = 0; m < 4; ++m)
#pragma unroll
        for (int n = 0; n < 4; ++n)
          acc[m][n] = __builtin_amdgcn_mfma_f32_16x16x32_bf16(af[m], bg[n], acc[m][n], 0, 0, 0);
    }
    __syncthreads();
  }
#pragma unroll
  for (int m = 0; m < 4; ++m)
#pragma unroll
    for (int n = 0; n < 4; ++n) {
      int r0 = wr + m * 16 + (lane >> 4) * 4;
      int c0 = bcol + wc + n * 16 + (lane & 15);
#pragma unroll
      for (int r = 0; r < 4; ++r)
        atomicAdd(&C[(size_t)(r0 + r) * 512 + c0], acc[m][n][r]);
    }
}

__global__ void k_init_out(float* __restrict__ out, const float* __restrict__ bout) {
  int i = blockIdx.x * 256 + threadIdx.x;   // 128*512
  out[i] = bout[i & 511];
}

extern "C" void kernel_launch(void* const* d_in, const int* in_sizes, int n_in,
                              void* d_out, int out_size, void* d_ws, size_t ws_size,
                              hipStream_t stream) {
  const float* x    = (const float*)d_in[0];
  const float* W1   = (const float*)d_in[1];
  const float* b1   = (const float*)d_in[2];
  const float* W2   = (const float*)d_in[3];
  const float* b2   = (const float*)d_in[4];
  const float* Wout = (const float*)d_in[5];
  const float* bout = (const float*)d_in[6];
  float* out = (float*)d_out;
  (void)in_sizes; (void)n_in; (void)out_size;

  char* ws = (char*)d_ws;
  size_t off = 0;
  auto alloc = [&](size_t bytes) -> void* {
    void* p = ws + off;
    off += (bytes + 255) & ~(size_t)255;
    return p;
  };
  unsigned short* W1cat = (unsigned short*)alloc((size_t)2048 * 2048 * 2);  // 8 MiB
  signed char*    W2q   = (signed char*)alloc((size_t)2048 * 2048);         // 4 MiB
  float*          scl   = (float*)alloc((size_t)2048 * 4);                  // 8 KiB
  unsigned short* Wocat = (unsigned short*)alloc((size_t)512 * 4096 * 2);   // 4 MiB
  unsigned short* ACC   = (unsigned short*)alloc((size_t)128 * 2048 * 2);   // 0.5 MiB
  const size_t fixed = off;

  // largest row-chunk (multiple of 1024) whose Xcat (bf16x2) + S1 (u8) fit
  int rows_c = 16384;
  while (rows_c > 1024) {
    size_t per = (((size_t)rows_c * 2048 * 2 + 255) & ~(size_t)255) +
                 (((size_t)rows_c * 2048 + 255) & ~(size_t)255);
    if (fixed + per <= ws_size) break;
    rows_c >>= 1;
  }
  unsigned short* Xcat = (unsigned short*)alloc((size_t)rows_c * 2048 * 2);
  unsigned char*  S1c  = (unsigned char*)alloc((size_t)rows_c * 2048);

  // weight prep (once per call)
  k_split4<<<(2048 * 256 + 255) / 256, 256, 0, stream>>>((const float4*)W1, W1cat, 10,
                                                         (size_t)2048 * 256);
  k_quant_w2<<<2048, 256, 0, stream>>>(W2, W2q, scl);
  k_split4<<<(512 * 512 + 255) / 256, 256, 0, stream>>>((const float4*)Wout, Wocat, 11,
                                                        (size_t)512 * 512);

  const int nch = 16384 / rows_c;
  for (int c = 0; c < nch; ++c) {
    k_split4<<<rows_c, 256, 0, stream>>>((const float4*)(x + (size_t)c * rows_c * 1024),
                                         Xcat, 10, (size_t)rows_c * 256);
    k_gemm1_lif<<<dim3(rows_c / 256, 8), 512, 0, stream>>>(Xcat, W1cat, b1, S1c);
    k_gemm2_lif_i8<<<dim3(rows_c / 256, 8), 512, 0, stream>>>(
        (const signed char*)S1c, W2q, scl, b2, ACC, c * (rows_c / 128));
  }
  k_init_out<<<256, 256, 0, stream>>>(out, bout);
  k_gemm3<<<dim3(1, 4, 16), 256, 0, stream>>>(ACC, Wocat, out);
}

// Round 20
// 283.640 us; speedup vs baseline: 1.0493x; 1.0493x over previous
//
#include <hip/hip_runtime.h>

// SpikingNetwork: B=128 T=128 I=1024 H1=2048 H2=2048 O=512
// R20 = R18 revert (best verified: 283.9 us, absmax 0.0352). R19's BK=32
//   counted-vmcnt GEMM1 regressed (-10%: barrier count doubled, per-phase
//   overhead > saved drain stall) -> pre-committed revert.
// Final configuration:
//   GEMM1: 3-term split-bf16 (K'=3072), R13 schedule — 256x256 tile, 8
//     waves of 128x64, BK=64, 2x64KB LDS dbuf, gld_lds staging, row-XOR
//     swizzle, 4-phase lgkm-counted ds_read pipe, 2 bars/tile, setprio.
//   GEMM2: int8 MFMA 16x16x64 (2x rate; s1 binary exact, i32 accum exact,
//     W2 per-row int8 quant ~5e-3 injected at cur2 = proven-benign), BK=64,
//     3x32KB slots, stage t+2, counted VMC(4)/tile.
//   Fused LIF epilogues in both GEMMs; GEMM3 2-term split-K atomic.

typedef unsigned long long u64;
typedef __attribute__((ext_vector_type(4))) float f32x4;
typedef __attribute__((ext_vector_type(8))) short bf16x8;
typedef __attribute__((ext_vector_type(4))) int i32x4;

__device__ __forceinline__ unsigned short f2bf(float f) {
  unsigned u = __float_as_uint(f);
  u += 0x7fff + ((u >> 16) & 1);   // RNE
  return (unsigned short)(u >> 16);
}
__device__ __forceinline__ float bf2f(unsigned short h) {
  return __uint_as_float(((unsigned)h) << 16);
}
__device__ __forceinline__ void gld_lds16(const void* g, void* l) {
  __builtin_amdgcn_global_load_lds((const __attribute__((address_space(1))) void*)g,
                                   (__attribute__((address_space(3))) void*)l, 16, 0, 0);
}

// src: R x K f32 (K = 1<<lgK) -> dst: R x 2K bf16 rows [hi | lo], 4 elem/thread
__global__ void k_split4(const float4* __restrict__ src, unsigned short* __restrict__ dst,
                         int lgK, size_t total4) {
  size_t i = (size_t)blockIdx.x * 256 + threadIdx.x;
  if (i >= total4) return;
  const int K = 1 << lgK;
  size_t e = i << 2;
  size_t r = e >> lgK;
  int k = (int)(e & (size_t)(K - 1));
  float4 f = src[i];
  unsigned short h0 = f2bf(f.x), h1 = f2bf(f.y), h2 = f2bf(f.z), h3 = f2bf(f.w);
  unsigned short l0 = f2bf(f.x - bf2f(h0)), l1 = f2bf(f.y - bf2f(h1));
  unsigned short l2 = f2bf(f.z - bf2f(h2)), l3 = f2bf(f.w - bf2f(h3));
  size_t o = (r << (lgK + 1)) + (size_t)k;
  *(u64*)(dst + o)     = (u64)h0 | ((u64)h1 << 16) | ((u64)h2 << 32) | ((u64)h3 << 48);
  *(u64*)(dst + o + K) = (u64)l0 | ((u64)l1 << 16) | ((u64)l2 << 32) | ((u64)l3 << 48);
}

// per-row int8 quantization of W2 (2048 x 2048): one block per row
__global__ void k_quant_w2(const float* __restrict__ W2, signed char* __restrict__ W2q,
                           float* __restrict__ scl) {
  __shared__ float red[4];
  const int r = blockIdx.x;
  const int tid = threadIdx.x;
  const float* row = W2 + (size_t)r * 2048;
  float vbuf[8];
  float mx = 0.f;
#pragma unroll
  for (int k = 0; k < 8; ++k) {
    vbuf[k] = row[tid + k * 256];
    mx = fmaxf(mx, fabsf(vbuf[k]));
  }
#pragma unroll
  for (int o = 32; o; o >>= 1) mx = fmaxf(mx, __shfl_xor(mx, o));
  if ((tid & 63) == 0) red[tid >> 6] = mx;
  __syncthreads();
  mx = fmaxf(fmaxf(red[0], red[1]), fmaxf(red[2], red[3]));
  mx = fmaxf(mx, 1e-20f);
  const float inv = 127.f / mx;
  if (tid == 0) scl[r] = mx * (1.f / 127.f);
#pragma unroll
  for (int k = 0; k < 8; ++k)
    W2q[(size_t)r * 2048 + tid + k * 256] = (signed char)__float2int_rn(vbuf[k] * inv);
}

// 4x ds_read_b128, stride 2048 B (bf16 16-row frag groups)
#define DSR4(D, BASE)                                                          \
  do {                                                                         \
    asm volatile("ds_read_b128 %0, %1" : "=v"(D[0]) : "v"(BASE));              \
    asm volatile("ds_read_b128 %0, %1 offset:2048" : "=v"(D[1]) : "v"(BASE));  \
    asm volatile("ds_read_b128 %0, %1 offset:4096" : "=v"(D[2]) : "v"(BASE));  \
    asm volatile("ds_read_b128 %0, %1 offset:6144" : "=v"(D[3]) : "v"(BASE));  \
  } while (0)
// 4x ds_read_b128, stride 1024 B (i8 16-row frag groups, 64B rows)
#define DSR4_I8(D, BASE)                                                       \
  do {                                                                         \
    asm volatile("ds_read_b128 %0, %1" : "=v"(D[0]) : "v"(BASE));              \
    asm volatile("ds_read_b128 %0, %1 offset:1024" : "=v"(D[1]) : "v"(BASE));  \
    asm volatile("ds_read_b128 %0, %1 offset:2048" : "=v"(D[2]) : "v"(BASE));  \
    asm volatile("ds_read_b128 %0, %1 offset:3072" : "=v"(D[3]) : "v"(BASE));  \
  } while (0)
#define WAITL(N)                                                               \
  do {                                                                         \
    asm volatile("s_waitcnt lgkmcnt(" #N ")" ::: "memory");                    \
    __builtin_amdgcn_sched_barrier(0);                                         \
  } while (0)
#define VMC(N)                                                                 \
  do {                                                                         \
    asm volatile("s_waitcnt vmcnt(" #N ")" ::: "memory");                      \
    __builtin_amdgcn_sched_barrier(0);                                         \
  } while (0)
#define BAR() __builtin_amdgcn_s_barrier()
#define SP1() __builtin_amdgcn_s_setprio(1)
#define SP0() __builtin_amdgcn_s_setprio(0)
#define MFMA16(MH, AF, BG)                                                     \
  _Pragma("unroll")                                                            \
  for (int m = 0; m < 4; ++m)                                                  \
    _Pragma("unroll")                                                          \
    for (int n = 0; n < 4; ++n)                                                \
      acc[(MH)*4 + m][n] = __builtin_amdgcn_mfma_f32_16x16x32_bf16(            \
          AF[m], BG[n], acc[(MH)*4 + m][n], 0, 0, 0);
#define MFMA16_I8(MH, AF, BG)                                                  \
  _Pragma("unroll")                                                            \
  for (int m = 0; m < 4; ++m)                                                  \
    _Pragma("unroll")                                                          \
    for (int n = 0; n < 4; ++n)                                                \
      acc[(MH)*4 + m][n] = __builtin_amdgcn_mfma_i32_16x16x64_i8(              \
          AF[m], BG[n], acc[(MH)*4 + m][n], 0, 0, 0);

// ---- GEMM1 + LIF1 (R13 schedule, 3-term split-bf16, K'=3072) ----
// out: S1 as u8 (0/1), [rows][2048] bytes.
__global__ __launch_bounds__(512, 2)
void k_gemm1_lif(const unsigned short* __restrict__ A,
                 const unsigned short* __restrict__ Bw,
                 const float* __restrict__ bias,
                 unsigned char* __restrict__ out) {
  __shared__ __align__(128) char lds[132096];
  const int NKT = 48;
  const int tid  = threadIdx.x;
  const int lane = tid & 63;
  const int w    = tid >> 6;
  const int wm = w >> 2, wn = w & 3;
  const int wr = wm * 128, wc = wn * 64;
  const int lrow = lane & 15, t4 = lane >> 4;
  const int brow = blockIdx.x * 256, bcol = blockIdx.y * 256;

  f32x4 acc[8][4];
#pragma unroll
  for (int m = 0; m < 8; ++m)
#pragma unroll
    for (int n = 0; n < 4; ++n) acc[m][n] = (f32x4){0.f, 0.f, 0.f, 0.f};

  int voffA[4], voffB[4];
  unsigned dstA[4], dstB[4];
#pragma unroll
  for (int j = 0; j < 4; ++j) {
    const int c = tid + j * 512;
    const int r = c >> 3;
    const int scol = ((c & 7) ^ (r & 7)) * 8;
    voffA[j] = (brow + r) * 2048 + scol;
    voffB[j] = (bcol + r) * 2048 + scol;
    dstA[j] = (unsigned)c * 16;
    dstB[j] = 32768u + (unsigned)c * 16;
  }
  auto stage_tile = [&](int tt) {
    if (tt >= NKT) return;
    const int kb = tt * 64;
    const int aoff = (kb < 1024) ? kb : kb - 1024;    // [Xhi,Xhi,Xlo]
    const int boff = (kb < 2048) ? kb : kb - 2048;    // [W1hi,W1lo,W1hi]
    const unsigned short* Ap = A + aoff;
    const unsigned short* Bp = Bw + boff;
    char* slot = lds + (tt & 1) * 65536;
#pragma unroll
    for (int j = 0; j < 4; ++j)
      gld_lds16(Ap + voffA[j], slot + dstA[j]);
#pragma unroll
    for (int j = 0; j < 4; ++j)
      gld_lds16(Bp + voffB[j], slot + dstB[j]);
  };

  const unsigned ldsb = (unsigned)(size_t)(__attribute__((address_space(3))) char*)lds;
  const unsigned cA   = (unsigned)((wr + lrow) * 128);
  const unsigned cB   = (unsigned)(32768 + (wc + lrow) * 128);
  const unsigned ch0  = (unsigned)(((t4) ^ (lrow & 7)) * 16);
  const unsigned ch1  = (unsigned)(((4 + t4) ^ (lrow & 7)) * 16);

  bf16x8 afA[4], afB[4], bgA[4], bgB[4];

  stage_tile(0);
  asm volatile("s_waitcnt vmcnt(0)" ::: "memory");
  BAR();
  DSR4(afA, ldsb + cA + ch0);
  DSR4(bgA, ldsb + cB + ch0);

#pragma unroll 1
  for (int t = 0; t < NKT; ++t) {
    const unsigned sA  = ldsb + (unsigned)((t & 1) * 65536);
    const unsigned sAn = ldsb + (unsigned)(((t + 1) & 1) * 65536);
    stage_tile(t + 1);
    DSR4(afB, sA + cA + 8192 + ch0);
    WAITL(4);
    SP1(); MFMA16(0, afA, bgA); SP0();
    DSR4(afA, sA + cA + ch1);
    DSR4(bgB, sA + cB + ch1);
    WAITL(8);
    SP1(); MFMA16(1, afB, bgA); SP0();
    DSR4(afB, sA + cA + 8192 + ch1);
    WAITL(4);
    SP1(); MFMA16(0, afA, bgB); SP0();
    asm volatile("s_waitcnt vmcnt(0)" ::: "memory");
    BAR();
    if (t + 1 < NKT) {
      DSR4(afA, sAn + cA + ch0);
      DSR4(bgA, sAn + cB + ch0);
      WAITL(8);
    } else {
      WAITL(0);
    }
    SP1(); MFMA16(1, afB, bgB); SP0();
    BAR();
  }

  // fused LIF1 epilogue: spikes as u8
  float* Ct = (float*)lds;
  const int colT  = tid & 255;
  const int batch = tid >> 8;
  const float bs = bias[bcol + colT];
  float v = 0.f;
  unsigned char* sp = out + (size_t)(brow + batch * 128) * 2048 + bcol + colT;
#pragma unroll
  for (int h = 0; h < 2; ++h) {
    __syncthreads();
#pragma unroll
    for (int mm = 0; mm < 4; ++mm) {
      const int m = h * 4 + mm;
#pragma unroll
      for (int n = 0; n < 4; ++n) {
        const int lr  = wm * 64 + mm * 16 + t4 * 4;
        const int col = wc + n * 16 + lrow;
#pragma unroll
        for (int r = 0; r < 4; ++r) Ct[(lr + r) * 258 + col] = acc[m][n][r];
      }
    }
    __syncthreads();
#pragma unroll 4
    for (int tl = 0; tl < 64; ++tl) {
      const float xx = Ct[(batch * 64 + tl) * 258 + colT] + bs;
      v = 0.9f * xx + v - ((xx > 1.0f) ? 1.0f : 0.0f);
      sp[(size_t)(h * 64 + tl) * 2048] = (v > 1.0f) ? 1 : 0;
    }
  }
}

// ---- GEMM2 + LIF2, int8 (2x MFMA rate; exact i32 accumulate) ----
__global__ __launch_bounds__(512, 2)
void k_gemm2_lif_i8(const signed char* __restrict__ A,
                    const signed char* __restrict__ Bq,
                    const float* __restrict__ scl,
                    const float* __restrict__ bias,
                    unsigned short* __restrict__ out, int b0) {
  __shared__ __align__(128) char lds[132096];  // 3x32KB slots; epi 128x258
  const int NKT = 32;
  const int tid  = threadIdx.x;
  const int lane = tid & 63;
  const int w    = tid >> 6;
  const int wm = w >> 2, wn = w & 3;
  const int wr = wm * 128, wc = wn * 64;
  const int lrow = lane & 15, t4 = lane >> 4;
  const int brow = blockIdx.x * 256, bcol = blockIdx.y * 256;

  i32x4 acc[8][4];
#pragma unroll
  for (int m = 0; m < 8; ++m)
#pragma unroll
    for (int n = 0; n < 4; ++n) acc[m][n] = (i32x4){0, 0, 0, 0};

  int voffA[2], voffB[2];
  unsigned dstA[2], dstB[2];
#pragma unroll
  for (int j = 0; j < 2; ++j) {
    const int c = tid + j * 512;             // 0..1023
    const int r = c >> 2;
    const int sc = ((c & 3) ^ ((r >> 1) & 3)) * 16;
    voffA[j] = (brow + r) * 2048 + sc;
    voffB[j] = (bcol + r) * 2048 + sc;
    dstA[j] = (unsigned)c * 16;
    dstB[j] = 16384u + (unsigned)c * 16;
  }
  auto stage_tile = [&](int tt) {
    if (tt >= NKT) return;
    const int kb = tt * 64;
    char* slot = lds + (tt % 3) * 32768;
#pragma unroll
    for (int j = 0; j < 2; ++j)
      gld_lds16(A + kb + voffA[j], slot + dstA[j]);
#pragma unroll
    for (int j = 0; j < 2; ++j)
      gld_lds16(Bq + kb + voffB[j], slot + dstB[j]);
  };

  const unsigned ldsb = (unsigned)(size_t)(__attribute__((address_space(3))) char*)lds;
  const unsigned cA  = (unsigned)((wr + lrow) * 64);
  const unsigned cB  = 16384u + (unsigned)((wc + lrow) * 64);
  const unsigned chi = (unsigned)((t4 ^ ((lrow >> 1) & 3)) * 16);

  i32x4 afA[4], afB[4], bgA[4], bgB[4];

  stage_tile(0); stage_tile(1);
  VMC(4);
  BAR();
  DSR4_I8(afA, ldsb + cA + chi);
  DSR4_I8(bgA, ldsb + cB + chi);

#define TILE_I8(T, BGC, BGN)                                                   \
  {                                                                            \
    const int tt = (T);                                                        \
    const unsigned s  = ldsb + (unsigned)((tt % 3) * 32768);                   \
    const unsigned sn = ldsb + (unsigned)(((tt + 1) % 3) * 32768);             \
    stage_tile(tt + 2);                                                        \
    if (tt + 2 < NKT) { VMC(4); } else { VMC(0); }                             \
    BAR();                                                                     \
    DSR4_I8(afB, s + cA + 4096 + chi);                                         \
    WAITL(4);                                                                  \
    SP1(); MFMA16_I8(0, afA, BGC); SP0();                                      \
    if (tt + 1 < NKT) {                                                        \
      DSR4_I8(afA, sn + cA + chi);                                             \
      DSR4_I8(BGN, sn + cB + chi);                                             \
      WAITL(8);                                                                \
    } else {                                                                   \
      WAITL(0);                                                                \
    }                                                                          \
    SP1(); MFMA16_I8(1, afB, BGC); SP0();                                      \
    BAR();                                                                     \
  }

#pragma unroll 1
  for (int t = 0; t < NKT; t += 2) {
    TILE_I8(t, bgA, bgB);
    TILE_I8(t + 1, bgB, bgA);
  }
#undef TILE_I8

  // fused LIF2 epilogue: acc i32 -> cur2 = acc*scl[col] + bias -> spike count
  int* Cti = (int*)lds;
  const int colT  = tid & 255;
  const int batch = tid >> 8;
  const float bs = bias[bcol + colT];
  const float sc = scl[bcol + colT];
  float v = 0.f;
  int cnt = 0;
#pragma unroll
  for (int h = 0; h < 2; ++h) {
    __syncthreads();
#pragma unroll
    for (int mm = 0; mm < 4; ++mm) {
      const int m = h * 4 + mm;
#pragma unroll
      for (int n = 0; n < 4; ++n) {
        const int lr  = wm * 64 + mm * 16 + t4 * 4;
        const int col = wc + n * 16 + lrow;
#pragma unroll
        for (int r = 0; r < 4; ++r) Cti[(lr + r) * 258 + col] = acc[m][n][r];
      }
    }
    __syncthreads();
#pragma unroll 4
    for (int tl = 0; tl < 64; ++tl) {
      const float xx = (float)Cti[(batch * 64 + tl) * 258 + colT] * sc + bs;
      v = 0.9f * xx + v - ((xx > 1.0f) ? 1.0f : 0.0f);
      cnt += (v > 1.0f);
    }
  }
  out[(size_t)(b0 + 2 * blockIdx.x + batch) * 2048 + bcol + colT] =
      f2bf((float)cnt * 0.0078125f);
}

// out(128x512) += ACC(128x2048 bf16) @ Wocat^T over K-slice z*256..+256, atomic
__global__ void k_gemm3(const unsigned short* __restrict__ A,
                        const unsigned short* __restrict__ B,
                        float* __restrict__ C) {
  __shared__ __align__(16) unsigned short Asm[128 * 64];
  __shared__ __align__(16) unsigned short Bsm[128 * 64];
  const int tid  = threadIdx.x;
  const int bcol = blockIdx.y * 128;
  const int k0   = blockIdx.z * 256;
  const int lane = tid & 63;
  const int w    = tid >> 6;
  const int wr = (w >> 1) * 64, wc = (w & 1) * 64;
  const int lrow = lane & 15, lk = (lane >> 4) * 8;

  f32x4 acc[4][4];
#pragma unroll
  for (int m = 0; m < 4; ++m)
#pragma unroll
    for (int n = 0; n < 4; ++n) acc[m][n] = (f32x4){0.f, 0.f, 0.f, 0.f};

  for (int kt = 0; kt < 4; ++kt) {
    const int kb = k0 + kt * 64;
#pragma unroll
    for (int i = 0; i < 4; ++i) {
      int c = tid + i * 256;
      int row = c >> 3, kc = (c & 7) * 8;
      gld_lds16(A + (size_t)row * 2048 + (kb & 2047) + kc, &Asm[c * 8]);
      gld_lds16(B + (size_t)(bcol + row) * 4096 + kb + kc, &Bsm[c * 8]);
    }
    __syncthreads();
#pragma unroll
    for (int ks = 0; ks < 2; ++ks) {
      bf16x8 af[4], bg[4];
#pragma unroll
      for (int m = 0; m < 4; ++m)
        af[m] = *(const bf16x8*)&Asm[(wr + m * 16 + lrow) * 64 + ks * 32 + lk];
#pragma unroll
      for (int n = 0; n < 4; ++n)
        bg[n] = *(const bf16x8*)&Bsm[(wc + n * 16 + lrow) * 64 + ks * 32 + lk];
#pragma unroll
      for (int m = 0; m < 4; ++m)
#pragma unroll
        for (int n = 0; n < 4; ++n)
          acc[m][n] = __builtin_amdgcn_mfma_f32_16x16x32_bf16(af[m], bg[n], acc[m][n], 0, 0, 0);
    }
    __syncthreads();
  }
#pragma unroll
  for (int m = 0; m < 4; ++m)
#pragma unroll
    for (int n = 0; n < 4; ++n) {
      int r0 = wr + m * 16 + (lane >> 4) * 4;
      int c0 = bcol + wc + n * 16 + (lane & 15);
#pragma unroll
      for (int r = 0; r < 4; ++r)
        atomicAdd(&C[(size_t)(r0 + r) * 512 + c0], acc[m][n][r]);
    }
}

__global__ void k_init_out(float* __restrict__ out, const float* __restrict__ bout) {
  int i = blockIdx.x * 256 + threadIdx.x;   // 128*512
  out[i] = bout[i & 511];
}

extern "C" void kernel_launch(void* const* d_in, const int* in_sizes, int n_in,
                              void* d_out, int out_size, void* d_ws, size_t ws_size,
                              hipStream_t stream) {
  const float* x    = (const float*)d_in[0];
  const float* W1   = (const float*)d_in[1];
  const float* b1   = (const float*)d_in[2];
  const float* W2   = (const float*)d_in[3];
  const float* b2   = (const float*)d_in[4];
  const float* Wout = (const float*)d_in[5];
  const float* bout = (const float*)d_in[6];
  float* out = (float*)d_out;
  (void)in_sizes; (void)n_in; (void)out_size;

  char* ws = (char*)d_ws;
  size_t off = 0;
  auto alloc = [&](size_t bytes) -> void* {
    void* p = ws + off;
    off += (bytes + 255) & ~(size_t)255;
    return p;
  };
  unsigned short* W1cat = (unsigned short*)alloc((size_t)2048 * 2048 * 2);  // 8 MiB
  signed char*    W2q   = (signed char*)alloc((size_t)2048 * 2048);         // 4 MiB
  float*          scl   = (float*)alloc((size_t)2048 * 4);                  // 8 KiB
  unsigned short* Wocat = (unsigned short*)alloc((size_t)512 * 4096 * 2);   // 4 MiB
  unsigned short* ACC   = (unsigned short*)alloc((size_t)128 * 2048 * 2);   // 0.5 MiB
  const size_t fixed = off;

  // largest row-chunk (multiple of 1024) whose Xcat (bf16x2) + S1 (u8) fit
  int rows_c = 16384;
  while (rows_c > 1024) {
    size_t per = (((size_t)rows_c * 2048 * 2 + 255) & ~(size_t)255) +
                 (((size_t)rows_c * 2048 + 255) & ~(size_t)255);
    if (fixed + per <= ws_size) break;
    rows_c >>= 1;
  }
  unsigned short* Xcat = (unsigned short*)alloc((size_t)rows_c * 2048 * 2);
  unsigned char*  S1c  = (unsigned char*)alloc((size_t)rows_c * 2048);

  // weight prep (once per call)
  k_split4<<<(2048 * 256 + 255) / 256, 256, 0, stream>>>((const float4*)W1, W1cat, 10,
                                                         (size_t)2048 * 256);
  k_quant_w2<<<2048, 256, 0, stream>>>(W2, W2q, scl);
  k_split4<<<(512 * 512 + 255) / 256, 256, 0, stream>>>((const float4*)Wout, Wocat, 11,
                                                        (size_t)512 * 512);

  const int nch = 16384 / rows_c;
  for (int c = 0; c < nch; ++c) {
    k_split4<<<rows_c, 256, 0, stream>>>((const float4*)(x + (size_t)c * rows_c * 1024),
                                         Xcat, 10, (size_t)rows_c * 256);
    k_gemm1_lif<<<dim3(rows_c / 256, 8), 512, 0, stream>>>(Xcat, W1cat, b1, S1c);
    k_gemm2_lif_i8<<<dim3(rows_c / 256, 8), 512, 0, stream>>>(
        (const signed char*)S1c, W2q, scl, b2, ACC, c * (rows_c / 128));
  }
  k_init_out<<<256, 256, 0, stream>>>(out, bout);
  k_gemm3<<<dim3(1, 4, 16), 256, 0, stream>>>(ACC, Wocat, out);
}